// Round 5
// baseline (280.144 us; speedup 1.0000x reference)
//
#include <hip/hip_runtime.h>
#include <hip/hip_bf16.h>

#define NQ 4096
#define NK 8192
#define NSPLIT 8
#define KSPAN (NK / NSPLIT)
#define BK 64

// 0.125 (1/sqrt(64)) * log2(e): scores in log2 domain; no max subtraction needed
// (|S| <= ~14 in log2 domain, exp2 can't overflow; scale cancels in O/l)
#define QSCALE 0.1803368801111204f

typedef short v8s __attribute__((ext_vector_type(8)));
typedef float v4f __attribute__((ext_vector_type(4)));

static __device__ __forceinline__ unsigned short f2bf(float f) {
    unsigned int u = __float_as_uint(f);
    u = (u + 0x7FFFu + ((u >> 16) & 1u)) >> 16;
    return (unsigned short)u;
}
static __device__ __forceinline__ float bf2f(unsigned short h) {
    return __uint_as_float(((unsigned int)h) << 16);
}
static __device__ __forceinline__ unsigned int pkbf(float a, float b) {
    union { __hip_bfloat162 h; unsigned int u; } cv;
    cv.h = __float22bfloat162_rn(make_float2(a, b));
    return cv.u;
}
static __device__ __forceinline__ void split8(const float* a, v8s& hi, v8s& lo) {
#pragma unroll
    for (int j = 0; j < 8; ++j) {
        unsigned short h = f2bf(a[j]);
        hi[j] = (short)h;
        lo[j] = (short)f2bf(a[j] - bf2f(h));
    }
}
// load pre-split W^T B-fragment (hi/lo planes, layout [(k0>>3)*256+col][8])
static __device__ __forceinline__ void wload(const unsigned short* __restrict__ H,
                                             const unsigned short* __restrict__ L,
                                             int k0, int col, v8s& wh, v8s& wl) {
    const size_t f = (size_t)((k0 >> 3) * 256 + col) * 8;
    wh = *(const v8s*)(H + f);
    wl = *(const v8s*)(L + f);
}

// ---- weight pre-split: f32 W[K][256] -> bf16 hi/lo planes in fragment layout
__global__ __launch_bounds__(256) void prep_kernel(
    const float* __restrict__ Wq, const float* __restrict__ Wk,
    const float* __restrict__ Wv, const float* __restrict__ Wo,
    unsigned short* __restrict__ WqH, unsigned short* __restrict__ WqL,
    unsigned short* __restrict__ WkH, unsigned short* __restrict__ WkL,
    unsigned short* __restrict__ WvH, unsigned short* __restrict__ WvL,
    unsigned short* __restrict__ WoH, unsigned short* __restrict__ WoL)
{
    const int tid = blockIdx.x * 256 + threadIdx.x;  // 20480 total
    const float* W;
    unsigned short *H, *L;
    int f;
    if (tid < 8192)        { W = Wq; H = WqH; L = WqL; f = tid; }
    else if (tid < 10240)  { W = Wk; H = WkH; L = WkL; f = tid - 8192; }
    else if (tid < 12288)  { W = Wv; H = WvH; L = WvL; f = tid - 10240; }
    else                   { W = Wo; H = WoH; L = WoL; f = tid - 12288; }
    const int col = f & 255, k0 = (f >> 8) << 3;
    float wv[8];
#pragma unroll
    for (int j = 0; j < 8; ++j) wv[j] = W[(size_t)(k0 + j) * 256 + col];
    v8s hi, lo;
    split8(wv, hi, lo);
    *(v8s*)(H + (size_t)f * 8) = hi;
    *(v8s*)(L + (size_t)f * 8) = lo;
}

// ---- fused QKV projection with pre-split weights
__global__ __launch_bounds__(256) void qkv_kernel(
    const float* __restrict__ query, const float* __restrict__ key,
    const float* __restrict__ value,
    const unsigned short* __restrict__ WqH, const unsigned short* __restrict__ WqL,
    const unsigned short* __restrict__ WkH, const unsigned short* __restrict__ WkL,
    const unsigned short* __restrict__ WvH, const unsigned short* __restrict__ WvL,
    const float* __restrict__ bq, const float* __restrict__ bk,
    const float* __restrict__ bv,
    unsigned short* __restrict__ Qb, unsigned short* __restrict__ Kb,
    unsigned short* __restrict__ Vt, const int* __restrict__ nexp)
{
    const int b = blockIdx.x;
    const int t = threadIdx.x, w = t >> 6, lane = t & 63;
    const int quad = lane >> 4, l16 = lane & 15;
    const int colbase = w * 64;

    if (b < 256) {
        const int n0 = b * 16;
        v4f acc[4];
#pragma unroll
        for (int ct = 0; ct < 4; ++ct) {
            const float bb = bq[colbase + ct * 16 + l16];
            acc[ct] = v4f{bb, bb, bb, bb};
        }
        const float* arow = query + (size_t)(n0 + l16) * 256 + quad * 8;
#pragma unroll
        for (int k0 = 0; k0 < 256; k0 += 32) {
            float av[8];
            *(float4*)av = *(const float4*)(arow + k0);
            *(float4*)(av + 4) = *(const float4*)(arow + k0 + 4);
            v8s ah, al;
            split8(av, ah, al);
#pragma unroll
            for (int ct = 0; ct < 4; ++ct) {
                v8s wh, wl;
                wload(WqH, WqL, k0 + quad * 8, colbase + ct * 16 + l16, wh, wl);
                acc[ct] = __builtin_amdgcn_mfma_f32_16x16x32_bf16(al, wh, acc[ct], 0, 0, 0);
                acc[ct] = __builtin_amdgcn_mfma_f32_16x16x32_bf16(ah, wl, acc[ct], 0, 0, 0);
                acc[ct] = __builtin_amdgcn_mfma_f32_16x16x32_bf16(ah, wh, acc[ct], 0, 0, 0);
            }
        }
#pragma unroll
        for (int ct = 0; ct < 4; ++ct) {
            const int d = ct * 16 + l16;
            const int j = d >> 1;
            const float freq = exp2f(-(float)(j & 15) * 1.66096404744368f);
            const bool isx = (j < 16), odd = (d & 1);
#pragma unroll
            for (int r = 0; r < 4; ++r) {
                const int p = n0 + quad * 4 + r;
                const float tpos = isx ? (float)(p & 63) : (float)(p >> 6);
                float sn, cs;
                __sincosf(tpos * freq, &sn, &cs);
                const float x = acc[ct][r];
                const float xp = __shfl_xor(x, 1, 64);
                const float y = odd ? fmaf(x, cs, xp * sn) : fmaf(x, cs, -xp * sn);
                Qb[((size_t)(w * NQ + p) << 6) + d] = f2bf(y * QSCALE);
            }
        }
    } else {
        const bool isK = (b < 768);
        const int n0 = (isK ? (b - 256) : (b - 768)) * 16;
        const float* X = isK ? key : value;
        const unsigned short* WH = isK ? WkH : WvH;
        const unsigned short* WL = isK ? WkL : WvL;
        const float* bias = isK ? bk : bv;
        v4f acc[4];
#pragma unroll
        for (int ct = 0; ct < 4; ++ct) {
            const float bb = bias[colbase + ct * 16 + l16];
            acc[ct] = v4f{bb, bb, bb, bb};
        }
        const float* arow = X + (size_t)(n0 + l16) * 64 + quad * 8;
#pragma unroll
        for (int k0 = 0; k0 < 64; k0 += 32) {
            float av[8];
            *(float4*)av = *(const float4*)(arow + k0);
            *(float4*)(av + 4) = *(const float4*)(arow + k0 + 4);
            v8s ah, al;
            split8(av, ah, al);
#pragma unroll
            for (int ct = 0; ct < 4; ++ct) {
                v8s wh, wl;
                wload(WH, WL, k0 + quad * 8, colbase + ct * 16 + l16, wh, wl);
                acc[ct] = __builtin_amdgcn_mfma_f32_16x16x32_bf16(al, wh, acc[ct], 0, 0, 0);
                acc[ct] = __builtin_amdgcn_mfma_f32_16x16x32_bf16(ah, wl, acc[ct], 0, 0, 0);
                acc[ct] = __builtin_amdgcn_mfma_f32_16x16x32_bf16(ah, wh, acc[ct], 0, 0, 0);
            }
        }
        if (isK) {
            const int nro = NK - *nexp;
#pragma unroll
            for (int ct = 0; ct < 4; ++ct) {
                const int d = ct * 16 + l16;
                const int j = d >> 1;
                const float freq = exp2f(-(float)(j & 15) * 1.66096404744368f);
                const bool isx = (j < 16), odd = (d & 1);
#pragma unroll
                for (int r = 0; r < 4; ++r) {
                    const int p = n0 + quad * 4 + r;
                    const int pc = p & 4095;
                    const float tpos = isx ? (float)(pc & 63) : (float)(pc >> 6);
                    float sn, cs;
                    __sincosf(tpos * freq, &sn, &cs);
                    const float x = acc[ct][r];
                    const float xp = __shfl_xor(x, 1, 64);
                    float y = odd ? fmaf(x, cs, xp * sn) : fmaf(x, cs, -xp * sn);
                    y = (p < nro) ? y : x;
                    Kb[((size_t)(w * NK + p) << 6) + d] = f2bf(y);
                }
            }
        } else {
#pragma unroll
            for (int ct = 0; ct < 4; ++ct) {
                const int col = colbase + ct * 16 + l16;
                uint2 u = make_uint2(pkbf(acc[ct][0], acc[ct][1]),
                                     pkbf(acc[ct][2], acc[ct][3]));
                *(uint2*)(Vt + (size_t)col * NK + n0 + quad * 4) = u;
            }
        }
    }
}

// ---- flash attention: 1024 blocks = qt(32) x h(4) x s(8); 4 waves x 32 q-rows
// R5: NO LDS, NO barriers. Kb/Vt are L2/L3-resident (8 MB); each wave reads its
// K/V fragments directly from global with the same lane->element mapping the LDS
// path used (swizzles dropped: they existed only for LDS banking; the sigma
// permutation folds into a +4*quad element offset on V). Waves run fully
// decoupled -> no lockstep stalls; latency hidden by TLP + 24 indep loads/tile.
__global__ __launch_bounds__(256) void attn_kernel(
    const unsigned short* __restrict__ Qb, const unsigned short* __restrict__ Kb,
    const unsigned short* __restrict__ Vt, unsigned short* __restrict__ Opart,
    float* __restrict__ Lbuf)
{
    const int blk = blockIdx.x;
    const int s = blk & 7, h = (blk >> 3) & 3, qt = blk >> 5;
    const int t = threadIdx.x;
    const int w = t >> 6, lane = t & 63;
    const int quad = lane >> 4, l16 = lane & 15;

    const int q0 = qt * 128 + w * 32;
    v8s qf[2][2];
#pragma unroll
    for (int g = 0; g < 2; ++g) {
        const unsigned short* qr = Qb + ((size_t)(h * NQ + q0 + g * 16 + l16) << 6) + quad * 8;
        qf[g][0] = *(const v8s*)qr;
        qf[g][1] = *(const v8s*)(qr + 32);
    }

    v4f O[4][2];
#pragma unroll
    for (int dt = 0; dt < 4; ++dt)
#pragma unroll
        for (int g = 0; g < 2; ++g) O[dt][g] = v4f{0.f, 0.f, 0.f, 0.f};
    float psum[2] = {0.f, 0.f};

    // K row pointer for (k + l16): row*64 + quad*8 elements (16B aligned)
    const unsigned short* Krow = Kb + (((size_t)h * NK + s * KSPAN + l16) << 6) + quad * 8;
    // V row pointer for d-row l16: +4*quad carries the sigma permutation
    const unsigned short* Vrow = Vt + (size_t)(h * 64 + l16) * NK + s * KSPAN + quad * 4;

    for (int k0 = 0; k0 < KSPAN; k0 += BK) {
        // S^T = K Q^T ; exp2 immediately (no max); pack P into B-fragments in-regs
        v8s pf[2][2]; // [g][t]: slots 0-3 <- e[2t][0..3], slots 4-7 <- e[2t+1][0..3]
#pragma unroll
        for (int tt = 0; tt < 4; ++tt) {
            const unsigned short* kr = Krow + ((size_t)(k0 + tt * 16) << 6);
            const v8s kf0 = *(const v8s*)kr;
            const v8s kf1 = *(const v8s*)(kr + 32);
#pragma unroll
            for (int g = 0; g < 2; ++g) {
                v4f a = v4f{0.f, 0.f, 0.f, 0.f};
                a = __builtin_amdgcn_mfma_f32_16x16x32_bf16(kf0, qf[g][0], a, 0, 0, 0);
                a = __builtin_amdgcn_mfma_f32_16x16x32_bf16(kf1, qf[g][1], a, 0, 0, 0);
                const float e0 = __builtin_amdgcn_exp2f(a[0]);
                const float e1 = __builtin_amdgcn_exp2f(a[1]);
                const float e2 = __builtin_amdgcn_exp2f(a[2]);
                const float e3 = __builtin_amdgcn_exp2f(a[3]);
                psum[g] += (e0 + e1) + (e2 + e3);
                unsigned int* pp = (unsigned int*)&pf[g][tt >> 1];
                pp[(tt & 1) * 2 + 0] = pkbf(e0, e1);
                pp[(tt & 1) * 2 + 1] = pkbf(e2, e3);
            }
        }

        // O^T += V^T P^T ; sigma-permuted V fragments straight from global:
        // kloc = 32*tv + 16*h2 + 4*quad + rr  (rr = 4 contiguous bf16 = 8B load)
#pragma unroll
        for (int dt = 0; dt < 4; ++dt) {
            const unsigned short* vr = Vrow + (size_t)(dt * 16) * NK + k0;
#pragma unroll
            for (int tv = 0; tv < 2; ++tv) {
                union { v8s s; uint2 u[2]; } vv;
                vv.u[0] = *(const uint2*)(vr + tv * 32);
                vv.u[1] = *(const uint2*)(vr + tv * 32 + 16);
#pragma unroll
                for (int g = 0; g < 2; ++g)
                    O[dt][g] = __builtin_amdgcn_mfma_f32_16x16x32_bf16(vv.s, pf[g][tv], O[dt][g], 0, 0, 0);
            }
        }
    }

#pragma unroll
    for (int g = 0; g < 2; ++g) {
        float p = psum[g];
        p += __shfl_xor(p, 16, 64);
        p += __shfl_xor(p, 32, 64);
        psum[g] = p;
    }
    unsigned short* Ob = Opart + (size_t)blk * 8192;
#pragma unroll
    for (int g = 0; g < 2; ++g) {
        const int row = w * 32 + g * 16 + l16;
#pragma unroll
        for (int dt = 0; dt < 4; ++dt) {
            uint2 u = make_uint2(pkbf(O[dt][g][0], O[dt][g][1]),
                                 pkbf(O[dt][g][2], O[dt][g][3]));
            *(uint2*)(Ob + row * 64 + dt * 16 + quad * 4) = u;
        }
        if (quad == 0) Lbuf[blk * 128 + row] = psum[g];
    }
}

// ---- fused split-reduce + 1/l + output projection (NSPLIT=8).
// 256 blocks x 512 threads. Phase 1: reduce 16 rows over 8 splits, normalize,
// split to bf16 hi/lo A-planes in LDS. Phase 2: 8 waves x 32 cols GEMM.
__global__ __launch_bounds__(512) void oproj_kernel(
    const unsigned short* __restrict__ Opart, const float* __restrict__ Lbuf,
    const unsigned short* __restrict__ WoH, const unsigned short* __restrict__ WoL,
    const float* __restrict__ bo, float* __restrict__ out)
{
    __shared__ alignas(16) unsigned short AH[16][264];
    __shared__ alignas(16) unsigned short AL[16][264];

    const int blk = blockIdx.x;       // 16 rows per block
    const int n0 = blk * 16;
    const int qt = n0 >> 7, rr0 = n0 & 127;
    const int t = threadIdx.x;

    {   // phase 1
        const int row = t >> 5;        // 0..15
        const int d0 = (t & 31) * 8;   // 0..248 (stays within one head: 8 | 64)
        const int h = d0 >> 6, dd0 = d0 & 63;
        const int rr = rr0 + row;
        const int base = qt * 32 + h * 8;   // attn blk = qt*32 + h*8 + s
        const unsigned short* op = Opart + (size_t)base * 8192 + rr * 64 + dd0;
        float lsum = 0.f;
        float o[8] = {0.f, 0.f, 0.f, 0.f, 0.f, 0.f, 0.f, 0.f};
#pragma unroll
        for (int s = 0; s < NSPLIT; ++s) {
            lsum += Lbuf[(base + s) * 128 + rr];
            v8s a = *(const v8s*)(op + (size_t)s * 8192);
#pragma unroll
            for (int j = 0; j < 8; ++j) o[j] += bf2f((unsigned short)a[j]);
        }
        const float inv = 1.f / lsum;
#pragma unroll
        for (int j = 0; j < 8; ++j) o[j] *= inv;
        v8s hi, lo;
        split8(o, hi, lo);
        *(v8s*)&AH[row][d0] = hi;
        *(v8s*)&AL[row][d0] = lo;
    }
    __syncthreads();

    // phase 2: [16 x 256] @ [256 x 256] GEMM, 8 waves x 32 cols
    const int w = t >> 6, lane = t & 63;
    const int quad = lane >> 4, l16 = lane & 15;
    const int colbase = w * 32;
    v4f acc[2];
#pragma unroll
    for (int ct = 0; ct < 2; ++ct) {
        const float bb = bo[colbase + ct * 16 + l16];
        acc[ct] = v4f{bb, bb, bb, bb};
    }
#pragma unroll
    for (int k0 = 0; k0 < 256; k0 += 32) {
        const v8s ah = *(const v8s*)&AH[l16][k0 + quad * 8];
        const v8s al = *(const v8s*)&AL[l16][k0 + quad * 8];
#pragma unroll
        for (int ct = 0; ct < 2; ++ct) {
            v8s wh, wl;
            wload(WoH, WoL, k0 + quad * 8, colbase + ct * 16 + l16, wh, wl);
            acc[ct] = __builtin_amdgcn_mfma_f32_16x16x32_bf16(al, wh, acc[ct], 0, 0, 0);
            acc[ct] = __builtin_amdgcn_mfma_f32_16x16x32_bf16(ah, wl, acc[ct], 0, 0, 0);
            acc[ct] = __builtin_amdgcn_mfma_f32_16x16x32_bf16(ah, wh, acc[ct], 0, 0, 0);
        }
    }
#pragma unroll
    for (int ct = 0; ct < 2; ++ct)
#pragma unroll
        for (int r = 0; r < 4; ++r)
            out[(size_t)(n0 + quad * 4 + r) * 256 + colbase + ct * 16 + l16] = acc[ct][r];
}

extern "C" void kernel_launch(void* const* d_in, const int* in_sizes, int n_in,
                              void* d_out, int out_size, void* d_ws, size_t ws_size,
                              hipStream_t stream) {
    const float* query = (const float*)d_in[0];
    const float* key   = (const float*)d_in[1];
    const float* value = (const float*)d_in[2];
    const float* Wq    = (const float*)d_in[3];
    const float* bq    = (const float*)d_in[4];
    const float* Wk    = (const float*)d_in[5];
    const float* bk    = (const float*)d_in[6];
    const float* Wv    = (const float*)d_in[7];
    const float* bv    = (const float*)d_in[8];
    const float* Wo    = (const float*)d_in[9];
    const float* bo    = (const float*)d_in[10];
    const int*   nex   = (const int*)d_in[11];

    char* ws = (char*)d_ws;
    const size_t MB = 1024 * 1024;
    unsigned short* Qb    = (unsigned short*)(ws);                    // 2 MB
    unsigned short* Kb    = (unsigned short*)(ws + 2 * MB);           // 4 MB
    unsigned short* Vt    = (unsigned short*)(ws + 6 * MB);           // 4 MB
    unsigned short* Opart = (unsigned short*)(ws + 10 * MB);          // 16 MB bf16 (8 splits)
    float* Lbuf           = (float*)(ws + 26 * MB);                   // 512 KB
    unsigned short* Wpl   = (unsigned short*)(ws + 26 * MB + 512 * 1024);  // 640 KB
    unsigned short* WqH = Wpl;
    unsigned short* WqL = Wpl + 65536;
    unsigned short* WkH = Wpl + 131072;
    unsigned short* WkL = Wpl + 147456;
    unsigned short* WvH = Wpl + 163840;
    unsigned short* WvL = Wpl + 180224;
    unsigned short* WoH = Wpl + 196608;
    unsigned short* WoL = Wpl + 262144;
    float* out = (float*)d_out;

    prep_kernel<<<80, 256, 0, stream>>>(Wq, Wk, Wv, Wo,
                                        WqH, WqL, WkH, WkL, WvH, WvL, WoH, WoL);
    qkv_kernel<<<1280, 256, 0, stream>>>(query, key, value,
                                         WqH, WqL, WkH, WkL, WvH, WvL,
                                         bq, bk, bv, Qb, Kb, Vt, nex);
    attn_kernel<<<1024, 256, 0, stream>>>(Qb, Kb, Vt, Opart, Lbuf);
    oproj_kernel<<<256, 512, 0, stream>>>(Opart, Lbuf, WoH, WoL, bo, out);
}

// Round 6
// 154.542 us; speedup vs baseline: 1.8127x; 1.8127x over previous
//
#include <hip/hip_runtime.h>
#include <hip/hip_bf16.h>

#define NQ 4096
#define NK 8192
#define NSPLIT 8
#define KSPAN (NK / NSPLIT)
#define BK 64

// 0.125 (1/sqrt(64)) * log2(e): scores in log2 domain; no max subtraction needed
// (|S| <= ~14 in log2 domain, exp2 can't overflow; scale cancels in O/l)
#define QSCALE 0.1803368801111204f

typedef short v8s __attribute__((ext_vector_type(8)));
typedef float v4f __attribute__((ext_vector_type(4)));

static __device__ __forceinline__ unsigned short f2bf(float f) {
    unsigned int u = __float_as_uint(f);
    u = (u + 0x7FFFu + ((u >> 16) & 1u)) >> 16;
    return (unsigned short)u;
}
static __device__ __forceinline__ float bf2f(unsigned short h) {
    return __uint_as_float(((unsigned int)h) << 16);
}
static __device__ __forceinline__ unsigned int pkbf(float a, float b) {
    union { __hip_bfloat162 h; unsigned int u; } cv;
    cv.h = __float22bfloat162_rn(make_float2(a, b));
    return cv.u;
}
static __device__ __forceinline__ void split8(const float* a, v8s& hi, v8s& lo) {
#pragma unroll
    for (int j = 0; j < 8; ++j) {
        unsigned short h = f2bf(a[j]);
        hi[j] = (short)h;
        lo[j] = (short)f2bf(a[j] - bf2f(h));
    }
}
// load pre-split W^T B-fragment (hi/lo planes, layout [(k0>>3)*256+col][8])
static __device__ __forceinline__ void wload(const unsigned short* __restrict__ H,
                                             const unsigned short* __restrict__ L,
                                             int k0, int col, v8s& wh, v8s& wl) {
    const size_t f = (size_t)((k0 >> 3) * 256 + col) * 8;
    wh = *(const v8s*)(H + f);
    wl = *(const v8s*)(L + f);
}
// async global->LDS, 16B/lane; dest = uniform base + lane*16
static __device__ __forceinline__ void dma16(const unsigned short* g, unsigned short* l) {
    __builtin_amdgcn_global_load_lds(
        (const __attribute__((address_space(1))) unsigned int*)(const void*)g,
        (__attribute__((address_space(3))) unsigned int*)(void*)l, 16, 0, 0);
}

// ---- weight pre-split: f32 W[K][256] -> bf16 hi/lo planes in fragment layout
__global__ __launch_bounds__(256) void prep_kernel(
    const float* __restrict__ Wq, const float* __restrict__ Wk,
    const float* __restrict__ Wv, const float* __restrict__ Wo,
    unsigned short* __restrict__ WqH, unsigned short* __restrict__ WqL,
    unsigned short* __restrict__ WkH, unsigned short* __restrict__ WkL,
    unsigned short* __restrict__ WvH, unsigned short* __restrict__ WvL,
    unsigned short* __restrict__ WoH, unsigned short* __restrict__ WoL)
{
    const int tid = blockIdx.x * 256 + threadIdx.x;  // 20480 total
    const float* W;
    unsigned short *H, *L;
    int f;
    if (tid < 8192)        { W = Wq; H = WqH; L = WqL; f = tid; }
    else if (tid < 10240)  { W = Wk; H = WkH; L = WkL; f = tid - 8192; }
    else if (tid < 12288)  { W = Wv; H = WvH; L = WvL; f = tid - 10240; }
    else                   { W = Wo; H = WoH; L = WoL; f = tid - 12288; }
    const int col = f & 255, k0 = (f >> 8) << 3;
    float wv[8];
#pragma unroll
    for (int j = 0; j < 8; ++j) wv[j] = W[(size_t)(k0 + j) * 256 + col];
    v8s hi, lo;
    split8(wv, hi, lo);
    *(v8s*)(H + (size_t)f * 8) = hi;
    *(v8s*)(L + (size_t)f * 8) = lo;
}

// ---- fused QKV projection with pre-split weights
__global__ __launch_bounds__(256) void qkv_kernel(
    const float* __restrict__ query, const float* __restrict__ key,
    const float* __restrict__ value,
    const unsigned short* __restrict__ WqH, const unsigned short* __restrict__ WqL,
    const unsigned short* __restrict__ WkH, const unsigned short* __restrict__ WkL,
    const unsigned short* __restrict__ WvH, const unsigned short* __restrict__ WvL,
    const float* __restrict__ bq, const float* __restrict__ bk,
    const float* __restrict__ bv,
    unsigned short* __restrict__ Qb, unsigned short* __restrict__ Kb,
    unsigned short* __restrict__ Vt, const int* __restrict__ nexp)
{
    const int b = blockIdx.x;
    const int t = threadIdx.x, w = t >> 6, lane = t & 63;
    const int quad = lane >> 4, l16 = lane & 15;
    const int colbase = w * 64;

    if (b < 256) {
        const int n0 = b * 16;
        v4f acc[4];
#pragma unroll
        for (int ct = 0; ct < 4; ++ct) {
            const float bb = bq[colbase + ct * 16 + l16];
            acc[ct] = v4f{bb, bb, bb, bb};
        }
        const float* arow = query + (size_t)(n0 + l16) * 256 + quad * 8;
#pragma unroll
        for (int k0 = 0; k0 < 256; k0 += 32) {
            float av[8];
            *(float4*)av = *(const float4*)(arow + k0);
            *(float4*)(av + 4) = *(const float4*)(arow + k0 + 4);
            v8s ah, al;
            split8(av, ah, al);
#pragma unroll
            for (int ct = 0; ct < 4; ++ct) {
                v8s wh, wl;
                wload(WqH, WqL, k0 + quad * 8, colbase + ct * 16 + l16, wh, wl);
                acc[ct] = __builtin_amdgcn_mfma_f32_16x16x32_bf16(al, wh, acc[ct], 0, 0, 0);
                acc[ct] = __builtin_amdgcn_mfma_f32_16x16x32_bf16(ah, wl, acc[ct], 0, 0, 0);
                acc[ct] = __builtin_amdgcn_mfma_f32_16x16x32_bf16(ah, wh, acc[ct], 0, 0, 0);
            }
        }
#pragma unroll
        for (int ct = 0; ct < 4; ++ct) {
            const int d = ct * 16 + l16;
            const int j = d >> 1;
            const float freq = exp2f(-(float)(j & 15) * 1.66096404744368f);
            const bool isx = (j < 16), odd = (d & 1);
#pragma unroll
            for (int r = 0; r < 4; ++r) {
                const int p = n0 + quad * 4 + r;
                const float tpos = isx ? (float)(p & 63) : (float)(p >> 6);
                float sn, cs;
                __sincosf(tpos * freq, &sn, &cs);
                const float x = acc[ct][r];
                const float xp = __shfl_xor(x, 1, 64);
                const float y = odd ? fmaf(x, cs, xp * sn) : fmaf(x, cs, -xp * sn);
                Qb[((size_t)(w * NQ + p) << 6) + d] = f2bf(y * QSCALE);
            }
        }
    } else {
        const bool isK = (b < 768);
        const int n0 = (isK ? (b - 256) : (b - 768)) * 16;
        const float* X = isK ? key : value;
        const unsigned short* WH = isK ? WkH : WvH;
        const unsigned short* WL = isK ? WkL : WvL;
        const float* bias = isK ? bk : bv;
        v4f acc[4];
#pragma unroll
        for (int ct = 0; ct < 4; ++ct) {
            const float bb = bias[colbase + ct * 16 + l16];
            acc[ct] = v4f{bb, bb, bb, bb};
        }
        const float* arow = X + (size_t)(n0 + l16) * 64 + quad * 8;
#pragma unroll
        for (int k0 = 0; k0 < 64; k0 += 32) {
            float av[8];
            *(float4*)av = *(const float4*)(arow + k0);
            *(float4*)(av + 4) = *(const float4*)(arow + k0 + 4);
            v8s ah, al;
            split8(av, ah, al);
#pragma unroll
            for (int ct = 0; ct < 4; ++ct) {
                v8s wh, wl;
                wload(WH, WL, k0 + quad * 8, colbase + ct * 16 + l16, wh, wl);
                acc[ct] = __builtin_amdgcn_mfma_f32_16x16x32_bf16(al, wh, acc[ct], 0, 0, 0);
                acc[ct] = __builtin_amdgcn_mfma_f32_16x16x32_bf16(ah, wl, acc[ct], 0, 0, 0);
                acc[ct] = __builtin_amdgcn_mfma_f32_16x16x32_bf16(ah, wh, acc[ct], 0, 0, 0);
            }
        }
        if (isK) {
            const int nro = NK - *nexp;
#pragma unroll
            for (int ct = 0; ct < 4; ++ct) {
                const int d = ct * 16 + l16;
                const int j = d >> 1;
                const float freq = exp2f(-(float)(j & 15) * 1.66096404744368f);
                const bool isx = (j < 16), odd = (d & 1);
#pragma unroll
                for (int r = 0; r < 4; ++r) {
                    const int p = n0 + quad * 4 + r;
                    const int pc = p & 4095;
                    const float tpos = isx ? (float)(pc & 63) : (float)(pc >> 6);
                    float sn, cs;
                    __sincosf(tpos * freq, &sn, &cs);
                    const float x = acc[ct][r];
                    const float xp = __shfl_xor(x, 1, 64);
                    float y = odd ? fmaf(x, cs, xp * sn) : fmaf(x, cs, -xp * sn);
                    y = (p < nro) ? y : x;
                    Kb[((size_t)(w * NK + p) << 6) + d] = f2bf(y);
                }
            }
        } else {
            // interleaved k-layout within each 64-group: 4-elem piece s=(k&63)>>2
            // stored at 16B-chunk (4*(s>>3) + (s&3)), 8B-half ((s>>2)&1).
            // -> attn's PV reads each sigma-permuted V fragment as ONE b128.
            const int s0 = ((n0 & 63) >> 2) + quad;   // piece index 0..15
            const int tv = s0 >> 3, m = s0 & 7;
            const int koff = (n0 & ~63) + ((4 * tv + (m & 3)) << 3) + ((m >> 2) << 2);
#pragma unroll
            for (int ct = 0; ct < 4; ++ct) {
                const int col = colbase + ct * 16 + l16;
                uint2 u = make_uint2(pkbf(acc[ct][0], acc[ct][1]),
                                     pkbf(acc[ct][2], acc[ct][3]));
                *(uint2*)(Vt + (size_t)col * NK + koff) = u;
            }
        }
    }
}

// ---- flash attention: 1024 blocks = qt(32) x h(4) x s(8); 4 waves x 32 q-rows
// R6: R3's clean 2-phase double-buffer (one __syncthreads per tile) + V stored
// in interleaved k-layout so each PV fragment is a single aligned ds_read_b128
// (was 2x b64): 8 V-read insts/wave/tile instead of 16, same slot order.
__global__ __launch_bounds__(256) void attn_kernel(
    const unsigned short* __restrict__ Qb, const unsigned short* __restrict__ Kb,
    const unsigned short* __restrict__ Vt, unsigned short* __restrict__ Opart,
    float* __restrict__ Lbuf)
{
    __shared__ alignas(16) unsigned short Kl[2][64 * 64];
    __shared__ alignas(16) unsigned short Vl[2][64 * 64];

    const int blk = blockIdx.x;
    const int s = blk & 7, h = (blk >> 3) & 3, qt = blk >> 5;
    const int t = threadIdx.x;
    const int w = t >> 6, lane = t & 63;
    const int quad = lane >> 4, l16 = lane & 15;

    const int q0 = qt * 128 + w * 32;
    v8s qf[2][2];
#pragma unroll
    for (int g = 0; g < 2; ++g) {
        const unsigned short* qr = Qb + ((size_t)(h * NQ + q0 + g * 16 + l16) << 6) + quad * 8;
        qf[g][0] = *(const v8s*)qr;
        qf[g][1] = *(const v8s*)(qr + 32);
    }

    v4f O[4][2];
#pragma unroll
    for (int dt = 0; dt < 4; ++dt)
#pragma unroll
        for (int g = 0; g < 2; ++g) O[dt][g] = v4f{0.f, 0.f, 0.f, 0.f};
    float psum[2] = {0.f, 0.f};

    const unsigned short* Kbase = Kb + (((size_t)h * NK + s * KSPAN) << 6);
    const unsigned short* Vbase = Vt + (size_t)(h * 64) * NK + s * KSPAN;

    const int srow = lane >> 3;            // 0..7
    const int schunk = (lane & 7) ^ srow;  // swizzled 16B chunk
    const int c0off = ((quad ^ (l16 & 7)) * 8);
    const int c1off = c0off ^ 32;
    // single-b128 V fragment offsets (interleaved layout + storage swizzle)
    int voffN[2];
#pragma unroll
    for (int tv = 0; tv < 2; ++tv)
        voffN[tv] = ((4 * tv + quad) ^ (l16 & 7)) << 3;

    const int NT = KSPAN / BK;  // 16

    // prologue: stage tile 0 into buffer 0
#pragma unroll
    for (int half = 0; half < 2; ++half) {
        const int r0 = w * 16 + half * 8;
        dma16(Kbase + ((size_t)(r0 + srow) << 6) + schunk * 8, &Kl[0][r0 * 64]);
        dma16(Vbase + (size_t)(r0 + srow) * NK + schunk * 8, &Vl[0][r0 * 64]);
    }

    for (int it = 0; it < NT; ++it) {
        const int cur = it & 1;
        // barrier: (a) drains this wave's outstanding DMAs (compiler emits vmcnt(0)
        // before s_barrier) -> buf[cur] fully staged for all waves; (b) orders all
        // waves' previous-iter compute before buf[cur^1] is overwritten below.
        __syncthreads();

        // issue next tile's DMA now; it lands during this tile's compute
        if (it + 1 < NT) {
            const int k1 = (it + 1) * BK;
#pragma unroll
            for (int half = 0; half < 2; ++half) {
                const int r0 = w * 16 + half * 8;
                dma16(Kbase + ((size_t)(k1 + r0 + srow) << 6) + schunk * 8, &Kl[cur ^ 1][r0 * 64]);
                dma16(Vbase + (size_t)(r0 + srow) * NK + k1 + schunk * 8, &Vl[cur ^ 1][r0 * 64]);
            }
        }

        const unsigned short* Klc = &Kl[cur][0];
        const unsigned short* Vlc = &Vl[cur][0];

        // S^T = K Q^T ; exp2 immediately (no max); pack P into B-fragments in-regs
        v8s pf[2][2]; // [g][t]: slots 0-3 <- e[2t][0..3], slots 4-7 <- e[2t+1][0..3]
#pragma unroll
        for (int tt = 0; tt < 4; ++tt) {
            const unsigned short* kr = &Klc[(tt * 16 + l16) * 64];
            const v8s kf0 = *(const v8s*)(kr + c0off);
            const v8s kf1 = *(const v8s*)(kr + c1off);
#pragma unroll
            for (int g = 0; g < 2; ++g) {
                v4f a = v4f{0.f, 0.f, 0.f, 0.f};
                a = __builtin_amdgcn_mfma_f32_16x16x32_bf16(kf0, qf[g][0], a, 0, 0, 0);
                a = __builtin_amdgcn_mfma_f32_16x16x32_bf16(kf1, qf[g][1], a, 0, 0, 0);
                const float e0 = __builtin_amdgcn_exp2f(a[0]);
                const float e1 = __builtin_amdgcn_exp2f(a[1]);
                const float e2 = __builtin_amdgcn_exp2f(a[2]);
                const float e3 = __builtin_amdgcn_exp2f(a[3]);
                psum[g] += (e0 + e1) + (e2 + e3);
                unsigned int* pp = (unsigned int*)&pf[g][tt >> 1];
                pp[(tt & 1) * 2 + 0] = pkbf(e0, e1);
                pp[(tt & 1) * 2 + 1] = pkbf(e2, e3);
            }
        }

        // O^T += V^T P^T ; sigma-permuted V fragment = ONE b128 per (dt,tv)
#pragma unroll
        for (int dt = 0; dt < 4; ++dt) {
            const unsigned short* vr = &Vlc[(dt * 16 + l16) * 64];
#pragma unroll
            for (int tv = 0; tv < 2; ++tv) {
                const v8s vvs = *(const v8s*)(vr + voffN[tv]);
#pragma unroll
                for (int g = 0; g < 2; ++g)
                    O[dt][g] = __builtin_amdgcn_mfma_f32_16x16x32_bf16(vvs, pf[g][tv], O[dt][g], 0, 0, 0);
            }
        }
    }

#pragma unroll
    for (int g = 0; g < 2; ++g) {
        float p = psum[g];
        p += __shfl_xor(p, 16, 64);
        p += __shfl_xor(p, 32, 64);
        psum[g] = p;
    }
    unsigned short* Ob = Opart + (size_t)blk * 8192;
#pragma unroll
    for (int g = 0; g < 2; ++g) {
        const int row = w * 32 + g * 16 + l16;
#pragma unroll
        for (int dt = 0; dt < 4; ++dt) {
            uint2 u = make_uint2(pkbf(O[dt][g][0], O[dt][g][1]),
                                 pkbf(O[dt][g][2], O[dt][g][3]));
            *(uint2*)(Ob + row * 64 + dt * 16 + quad * 4) = u;
        }
        if (quad == 0) Lbuf[blk * 128 + row] = psum[g];
    }
}

// ---- fused split-reduce + 1/l + output projection (NSPLIT=8).
// 256 blocks x 512 threads. Phase 1: reduce 16 rows over 8 splits, normalize,
// split to bf16 hi/lo A-planes in LDS. Phase 2: 8 waves x 32 cols GEMM.
__global__ __launch_bounds__(512) void oproj_kernel(
    const unsigned short* __restrict__ Opart, const float* __restrict__ Lbuf,
    const unsigned short* __restrict__ WoH, const unsigned short* __restrict__ WoL,
    const float* __restrict__ bo, float* __restrict__ out)
{
    __shared__ alignas(16) unsigned short AH[16][264];
    __shared__ alignas(16) unsigned short AL[16][264];

    const int blk = blockIdx.x;       // 16 rows per block
    const int n0 = blk * 16;
    const int qt = n0 >> 7, rr0 = n0 & 127;
    const int t = threadIdx.x;

    {   // phase 1
        const int row = t >> 5;        // 0..15
        const int d0 = (t & 31) * 8;   // 0..248 (stays within one head: 8 | 64)
        const int h = d0 >> 6, dd0 = d0 & 63;
        const int rr = rr0 + row;
        const int base = qt * 32 + h * 8;   // attn blk = qt*32 + h*8 + s
        const unsigned short* op = Opart + (size_t)base * 8192 + rr * 64 + dd0;
        float lsum = 0.f;
        float o[8] = {0.f, 0.f, 0.f, 0.f, 0.f, 0.f, 0.f, 0.f};
#pragma unroll
        for (int s = 0; s < NSPLIT; ++s) {
            lsum += Lbuf[(base + s) * 128 + rr];
            v8s a = *(const v8s*)(op + (size_t)s * 8192);
#pragma unroll
            for (int j = 0; j < 8; ++j) o[j] += bf2f((unsigned short)a[j]);
        }
        const float inv = 1.f / lsum;
#pragma unroll
        for (int j = 0; j < 8; ++j) o[j] *= inv;
        v8s hi, lo;
        split8(o, hi, lo);
        *(v8s*)&AH[row][d0] = hi;
        *(v8s*)&AL[row][d0] = lo;
    }
    __syncthreads();

    // phase 2: [16 x 256] @ [256 x 256] GEMM, 8 waves x 32 cols
    const int w = t >> 6, lane = t & 63;
    const int quad = lane >> 4, l16 = lane & 15;
    const int colbase = w * 32;
    v4f acc[2];
#pragma unroll
    for (int ct = 0; ct < 2; ++ct) {
        const float bb = bo[colbase + ct * 16 + l16];
        acc[ct] = v4f{bb, bb, bb, bb};
    }
#pragma unroll
    for (int k0 = 0; k0 < 256; k0 += 32) {
        const v8s ah = *(const v8s*)&AH[l16][k0 + quad * 8];
        const v8s al = *(const v8s*)&AL[l16][k0 + quad * 8];
#pragma unroll
        for (int ct = 0; ct < 2; ++ct) {
            v8s wh, wl;
            wload(WoH, WoL, k0 + quad * 8, colbase + ct * 16 + l16, wh, wl);
            acc[ct] = __builtin_amdgcn_mfma_f32_16x16x32_bf16(al, wh, acc[ct], 0, 0, 0);
            acc[ct] = __builtin_amdgcn_mfma_f32_16x16x32_bf16(ah, wl, acc[ct], 0, 0, 0);
            acc[ct] = __builtin_amdgcn_mfma_f32_16x16x32_bf16(ah, wh, acc[ct], 0, 0, 0);
        }
    }
#pragma unroll
    for (int ct = 0; ct < 2; ++ct)
#pragma unroll
        for (int r = 0; r < 4; ++r)
            out[(size_t)(n0 + quad * 4 + r) * 256 + colbase + ct * 16 + l16] = acc[ct][r];
}

extern "C" void kernel_launch(void* const* d_in, const int* in_sizes, int n_in,
                              void* d_out, int out_size, void* d_ws, size_t ws_size,
                              hipStream_t stream) {
    const float* query = (const float*)d_in[0];
    const float* key   = (const float*)d_in[1];
    const float* value = (const float*)d_in[2];
    const float* Wq    = (const float*)d_in[3];
    const float* bq    = (const float*)d_in[4];
    const float* Wk    = (const float*)d_in[5];
    const float* bk    = (const float*)d_in[6];
    const float* Wv    = (const float*)d_in[7];
    const float* bv    = (const float*)d_in[8];
    const float* Wo    = (const float*)d_in[9];
    const float* bo    = (const float*)d_in[10];
    const int*   nex   = (const int*)d_in[11];

    char* ws = (char*)d_ws;
    const size_t MB = 1024 * 1024;
    unsigned short* Qb    = (unsigned short*)(ws);                    // 2 MB
    unsigned short* Kb    = (unsigned short*)(ws + 2 * MB);           // 4 MB
    unsigned short* Vt    = (unsigned short*)(ws + 6 * MB);           // 4 MB
    unsigned short* Opart = (unsigned short*)(ws + 10 * MB);          // 16 MB bf16 (8 splits)
    float* Lbuf           = (float*)(ws + 26 * MB);                   // 512 KB
    unsigned short* Wpl   = (unsigned short*)(ws + 26 * MB + 512 * 1024);  // 640 KB
    unsigned short* WqH = Wpl;
    unsigned short* WqL = Wpl + 65536;
    unsigned short* WkH = Wpl + 131072;
    unsigned short* WkL = Wpl + 147456;
    unsigned short* WvH = Wpl + 163840;
    unsigned short* WvL = Wpl + 180224;
    unsigned short* WoH = Wpl + 196608;
    unsigned short* WoL = Wpl + 262144;
    float* out = (float*)d_out;

    prep_kernel<<<80, 256, 0, stream>>>(Wq, Wk, Wv, Wo,
                                        WqH, WqL, WkH, WkL, WvH, WvL, WoH, WoL);
    qkv_kernel<<<1280, 256, 0, stream>>>(query, key, value,
                                         WqH, WqL, WkH, WkL, WvH, WvL,
                                         bq, bk, bv, Qb, Kb, Vt, nex);
    attn_kernel<<<1024, 256, 0, stream>>>(Qb, Kb, Vt, Opart, Lbuf);
    oproj_kernel<<<256, 512, 0, stream>>>(Opart, Lbuf, WoH, WoL, bo, out);
}

// Round 8
// 150.802 us; speedup vs baseline: 1.8577x; 1.0248x over previous
//
#include <hip/hip_runtime.h>
#include <hip/hip_bf16.h>

#define NQ 4096
#define NK 8192
#define NSPLIT 8
#define KSPAN (NK / NSPLIT)
#define BK 64

// 0.125 (1/sqrt(64)) * log2(e): scores in log2 domain; no max subtraction needed
// (|S| <= ~14 in log2 domain, exp2 can't overflow; scale cancels in O/l)
#define QSCALE 0.1803368801111204f

typedef short v8s __attribute__((ext_vector_type(8)));
typedef float v4f __attribute__((ext_vector_type(4)));

static __device__ __forceinline__ unsigned short f2bf(float f) {
    unsigned int u = __float_as_uint(f);
    u = (u + 0x7FFFu + ((u >> 16) & 1u)) >> 16;
    return (unsigned short)u;
}
static __device__ __forceinline__ float bf2f(unsigned short h) {
    return __uint_as_float(((unsigned int)h) << 16);
}
static __device__ __forceinline__ unsigned int pkbf(float a, float b) {
    union { __hip_bfloat162 h; unsigned int u; } cv;
    cv.h = __float22bfloat162_rn(make_float2(a, b));
    return cv.u;
}
static __device__ __forceinline__ void split8(const float* a, v8s& hi, v8s& lo) {
#pragma unroll
    for (int j = 0; j < 8; ++j) {
        unsigned short h = f2bf(a[j]);
        hi[j] = (short)h;
        lo[j] = (short)f2bf(a[j] - bf2f(h));
    }
}
// load pre-split W^T B-fragment (hi/lo planes, layout [(k0>>3)*256+col][8])
static __device__ __forceinline__ void wload(const unsigned short* __restrict__ H,
                                             const unsigned short* __restrict__ L,
                                             int k0, int col, v8s& wh, v8s& wl) {
    const size_t f = (size_t)((k0 >> 3) * 256 + col) * 8;
    wh = *(const v8s*)(H + f);
    wl = *(const v8s*)(L + f);
}
// async global->LDS, 16B/lane; dest = uniform base + lane*16
static __device__ __forceinline__ void dma16(const unsigned short* g, unsigned short* l) {
    __builtin_amdgcn_global_load_lds(
        (const __attribute__((address_space(1))) unsigned int*)(const void*)g,
        (__attribute__((address_space(3))) unsigned int*)(void*)l, 16, 0, 0);
}

// ---- weight pre-split: f32 W[K][256] -> bf16 hi/lo planes in fragment layout
__global__ __launch_bounds__(256) void prep_kernel(
    const float* __restrict__ Wq, const float* __restrict__ Wk,
    const float* __restrict__ Wv, const float* __restrict__ Wo,
    unsigned short* __restrict__ WqH, unsigned short* __restrict__ WqL,
    unsigned short* __restrict__ WkH, unsigned short* __restrict__ WkL,
    unsigned short* __restrict__ WvH, unsigned short* __restrict__ WvL,
    unsigned short* __restrict__ WoH, unsigned short* __restrict__ WoL)
{
    const int tid = blockIdx.x * 256 + threadIdx.x;  // 20480 total
    const float* W;
    unsigned short *H, *L;
    int f;
    if (tid < 8192)        { W = Wq; H = WqH; L = WqL; f = tid; }
    else if (tid < 10240)  { W = Wk; H = WkH; L = WkL; f = tid - 8192; }
    else if (tid < 12288)  { W = Wv; H = WvH; L = WvL; f = tid - 10240; }
    else                   { W = Wo; H = WoH; L = WoL; f = tid - 12288; }
    const int col = f & 255, k0 = (f >> 8) << 3;
    float wv[8];
#pragma unroll
    for (int j = 0; j < 8; ++j) wv[j] = W[(size_t)(k0 + j) * 256 + col];
    v8s hi, lo;
    split8(wv, hi, lo);
    *(v8s*)(H + (size_t)f * 8) = hi;
    *(v8s*)(L + (size_t)f * 8) = lo;
}

// ---- fused QKV projection with pre-split weights
__global__ __launch_bounds__(256) void qkv_kernel(
    const float* __restrict__ query, const float* __restrict__ key,
    const float* __restrict__ value,
    const unsigned short* __restrict__ WqH, const unsigned short* __restrict__ WqL,
    const unsigned short* __restrict__ WkH, const unsigned short* __restrict__ WkL,
    const unsigned short* __restrict__ WvH, const unsigned short* __restrict__ WvL,
    const float* __restrict__ bq, const float* __restrict__ bk,
    const float* __restrict__ bv,
    unsigned short* __restrict__ Qb, unsigned short* __restrict__ Kb,
    unsigned short* __restrict__ Vt, const int* __restrict__ nexp)
{
    const int b = blockIdx.x;
    const int t = threadIdx.x, w = t >> 6, lane = t & 63;
    const int quad = lane >> 4, l16 = lane & 15;
    const int colbase = w * 64;

    if (b < 256) {
        const int n0 = b * 16;
        v4f acc[4];
#pragma unroll
        for (int ct = 0; ct < 4; ++ct) {
            const float bb = bq[colbase + ct * 16 + l16];
            acc[ct] = v4f{bb, bb, bb, bb};
        }
        const float* arow = query + (size_t)(n0 + l16) * 256 + quad * 8;
#pragma unroll
        for (int k0 = 0; k0 < 256; k0 += 32) {
            float av[8];
            *(float4*)av = *(const float4*)(arow + k0);
            *(float4*)(av + 4) = *(const float4*)(arow + k0 + 4);
            v8s ah, al;
            split8(av, ah, al);
#pragma unroll
            for (int ct = 0; ct < 4; ++ct) {
                v8s wh, wl;
                wload(WqH, WqL, k0 + quad * 8, colbase + ct * 16 + l16, wh, wl);
                acc[ct] = __builtin_amdgcn_mfma_f32_16x16x32_bf16(al, wh, acc[ct], 0, 0, 0);
                acc[ct] = __builtin_amdgcn_mfma_f32_16x16x32_bf16(ah, wl, acc[ct], 0, 0, 0);
                acc[ct] = __builtin_amdgcn_mfma_f32_16x16x32_bf16(ah, wh, acc[ct], 0, 0, 0);
            }
        }
#pragma unroll
        for (int ct = 0; ct < 4; ++ct) {
            const int d = ct * 16 + l16;
            const int j = d >> 1;
            const float freq = exp2f(-(float)(j & 15) * 1.66096404744368f);
            const bool isx = (j < 16), odd = (d & 1);
#pragma unroll
            for (int r = 0; r < 4; ++r) {
                const int p = n0 + quad * 4 + r;
                const float tpos = isx ? (float)(p & 63) : (float)(p >> 6);
                float sn, cs;
                __sincosf(tpos * freq, &sn, &cs);
                const float x = acc[ct][r];
                const float xp = __shfl_xor(x, 1, 64);
                const float y = odd ? fmaf(x, cs, xp * sn) : fmaf(x, cs, -xp * sn);
                Qb[((size_t)(w * NQ + p) << 6) + d] = f2bf(y * QSCALE);
            }
        }
    } else {
        const bool isK = (b < 768);
        const int n0 = (isK ? (b - 256) : (b - 768)) * 16;
        const float* X = isK ? key : value;
        const unsigned short* WH = isK ? WkH : WvH;
        const unsigned short* WL = isK ? WkL : WvL;
        const float* bias = isK ? bk : bv;
        v4f acc[4];
#pragma unroll
        for (int ct = 0; ct < 4; ++ct) {
            const float bb = bias[colbase + ct * 16 + l16];
            acc[ct] = v4f{bb, bb, bb, bb};
        }
        const float* arow = X + (size_t)(n0 + l16) * 64 + quad * 8;
#pragma unroll
        for (int k0 = 0; k0 < 64; k0 += 32) {
            float av[8];
            *(float4*)av = *(const float4*)(arow + k0);
            *(float4*)(av + 4) = *(const float4*)(arow + k0 + 4);
            v8s ah, al;
            split8(av, ah, al);
#pragma unroll
            for (int ct = 0; ct < 4; ++ct) {
                v8s wh, wl;
                wload(WH, WL, k0 + quad * 8, colbase + ct * 16 + l16, wh, wl);
                acc[ct] = __builtin_amdgcn_mfma_f32_16x16x32_bf16(al, wh, acc[ct], 0, 0, 0);
                acc[ct] = __builtin_amdgcn_mfma_f32_16x16x32_bf16(ah, wl, acc[ct], 0, 0, 0);
                acc[ct] = __builtin_amdgcn_mfma_f32_16x16x32_bf16(ah, wh, acc[ct], 0, 0, 0);
            }
        }
        if (isK) {
            const int nro = NK - *nexp;
#pragma unroll
            for (int ct = 0; ct < 4; ++ct) {
                const int d = ct * 16 + l16;
                const int j = d >> 1;
                const float freq = exp2f(-(float)(j & 15) * 1.66096404744368f);
                const bool isx = (j < 16), odd = (d & 1);
#pragma unroll
                for (int r = 0; r < 4; ++r) {
                    const int p = n0 + quad * 4 + r;
                    const int pc = p & 4095;
                    const float tpos = isx ? (float)(pc & 63) : (float)(pc >> 6);
                    float sn, cs;
                    __sincosf(tpos * freq, &sn, &cs);
                    const float x = acc[ct][r];
                    const float xp = __shfl_xor(x, 1, 64);
                    float y = odd ? fmaf(x, cs, xp * sn) : fmaf(x, cs, -xp * sn);
                    y = (p < nro) ? y : x;
                    Kb[((size_t)(w * NK + p) << 6) + d] = f2bf(y);
                }
            }
        } else {
            // interleaved k-layout within each 64-group: 4-elem piece s=(k&63)>>2
            // stored at 16B-chunk (4*(s>>3) + (s&3)), 8B-half ((s>>2)&1).
            // -> attn's PV reads each sigma-permuted V fragment as ONE b128.
            const int s0 = ((n0 & 63) >> 2) + quad;   // piece index 0..15
            const int tv = s0 >> 3, m = s0 & 7;
            const int koff = (n0 & ~63) + ((4 * tv + (m & 3)) << 3) + ((m >> 2) << 2);
#pragma unroll
            for (int ct = 0; ct < 4; ++ct) {
                const int col = colbase + ct * 16 + l16;
                uint2 u = make_uint2(pkbf(acc[ct][0], acc[ct][1]),
                                     pkbf(acc[ct][2], acc[ct][3]));
                *(uint2*)(Vt + (size_t)col * NK + koff) = u;
            }
        }
    }
}

// ---- flash attention: 1024 blocks = qt(32) x h(4) x s(8); 4 waves x 32 q-rows
// R8: R6 + l-sum via ones-MFMA: l[q] = sum_k P[k][q] is a matmul-with-ones on
// the already-packed pf B-fragments -> 4 MFMA/tile on the idle matrix pipe
// replace 32 v_add on the saturated VALU pipe; final quad shfl-reduce gone
// (D's 16 rows identical; every lane holds the full sum for q=l16).
__global__ __launch_bounds__(256) void attn_kernel(
    const unsigned short* __restrict__ Qb, const unsigned short* __restrict__ Kb,
    const unsigned short* __restrict__ Vt, unsigned short* __restrict__ Opart,
    float* __restrict__ Lbuf)
{
    __shared__ alignas(16) unsigned short Kl[2][64 * 64];
    __shared__ alignas(16) unsigned short Vl[2][64 * 64];

    const int blk = blockIdx.x;
    const int s = blk & 7, h = (blk >> 3) & 3, qt = blk >> 5;
    const int t = threadIdx.x;
    const int w = t >> 6, lane = t & 63;
    const int quad = lane >> 4, l16 = lane & 15;

    const int q0 = qt * 128 + w * 32;
    v8s qf[2][2];
#pragma unroll
    for (int g = 0; g < 2; ++g) {
        const unsigned short* qr = Qb + ((size_t)(h * NQ + q0 + g * 16 + l16) << 6) + quad * 8;
        qf[g][0] = *(const v8s*)qr;
        qf[g][1] = *(const v8s*)(qr + 32);
    }

    v4f O[4][2];
#pragma unroll
    for (int dt = 0; dt < 4; ++dt)
#pragma unroll
        for (int g = 0; g < 2; ++g) O[dt][g] = v4f{0.f, 0.f, 0.f, 0.f};
    // l-sum accumulators (ones-MFMA); all 4 regs end up identical per lane
    v4f lsum[2];
    lsum[0] = v4f{0.f, 0.f, 0.f, 0.f};
    lsum[1] = v4f{0.f, 0.f, 0.f, 0.f};
    const short one_bf = (short)0x3F80;  // bf16 1.0
    const v8s vones = v8s{one_bf, one_bf, one_bf, one_bf, one_bf, one_bf, one_bf, one_bf};

    const unsigned short* Kbase = Kb + (((size_t)h * NK + s * KSPAN) << 6);
    const unsigned short* Vbase = Vt + (size_t)(h * 64) * NK + s * KSPAN;

    const int srow = lane >> 3;            // 0..7
    const int schunk = (lane & 7) ^ srow;  // swizzled 16B chunk
    const int c0off = ((quad ^ (l16 & 7)) * 8);
    const int c1off = c0off ^ 32;
    // single-b128 V fragment offsets (interleaved layout + storage swizzle)
    int voffN[2];
#pragma unroll
    for (int tv = 0; tv < 2; ++tv)
        voffN[tv] = ((4 * tv + quad) ^ (l16 & 7)) << 3;

    const int NT = KSPAN / BK;  // 16

    // prologue: stage tile 0 into buffer 0
#pragma unroll
    for (int half = 0; half < 2; ++half) {
        const int r0 = w * 16 + half * 8;
        dma16(Kbase + ((size_t)(r0 + srow) << 6) + schunk * 8, &Kl[0][r0 * 64]);
        dma16(Vbase + (size_t)(r0 + srow) * NK + schunk * 8, &Vl[0][r0 * 64]);
    }

    for (int it = 0; it < NT; ++it) {
        const int cur = it & 1;
        // barrier: (a) drains this wave's outstanding DMAs (compiler emits vmcnt(0)
        // before s_barrier) -> buf[cur] fully staged for all waves; (b) orders all
        // waves' previous-iter compute before buf[cur^1] is overwritten below.
        __syncthreads();

        // issue next tile's DMA now; it lands during this tile's compute
        if (it + 1 < NT) {
            const int k1 = (it + 1) * BK;
#pragma unroll
            for (int half = 0; half < 2; ++half) {
                const int r0 = w * 16 + half * 8;
                dma16(Kbase + ((size_t)(k1 + r0 + srow) << 6) + schunk * 8, &Kl[cur ^ 1][r0 * 64]);
                dma16(Vbase + (size_t)(r0 + srow) * NK + k1 + schunk * 8, &Vl[cur ^ 1][r0 * 64]);
            }
        }

        const unsigned short* Klc = &Kl[cur][0];
        const unsigned short* Vlc = &Vl[cur][0];

        // S^T = K Q^T ; exp2 immediately (no max); pack P into B-fragments in-regs
        v8s pf[2][2]; // [g][t]: slots 0-3 <- e[2t][0..3], slots 4-7 <- e[2t+1][0..3]
#pragma unroll
        for (int tt = 0; tt < 4; ++tt) {
            const unsigned short* kr = &Klc[(tt * 16 + l16) * 64];
            const v8s kf0 = *(const v8s*)(kr + c0off);
            const v8s kf1 = *(const v8s*)(kr + c1off);
#pragma unroll
            for (int g = 0; g < 2; ++g) {
                v4f a = v4f{0.f, 0.f, 0.f, 0.f};
                a = __builtin_amdgcn_mfma_f32_16x16x32_bf16(kf0, qf[g][0], a, 0, 0, 0);
                a = __builtin_amdgcn_mfma_f32_16x16x32_bf16(kf1, qf[g][1], a, 0, 0, 0);
                const float e0 = __builtin_amdgcn_exp2f(a[0]);
                const float e1 = __builtin_amdgcn_exp2f(a[1]);
                const float e2 = __builtin_amdgcn_exp2f(a[2]);
                const float e3 = __builtin_amdgcn_exp2f(a[3]);
                unsigned int* pp = (unsigned int*)&pf[g][tt >> 1];
                pp[(tt & 1) * 2 + 0] = pkbf(e0, e1);
                pp[(tt & 1) * 2 + 1] = pkbf(e2, e3);
            }
        }

        // l-sum: column sums of pf via ones-MFMA (replaces 32 VALU adds/tile)
#pragma unroll
        for (int g = 0; g < 2; ++g) {
            lsum[g] = __builtin_amdgcn_mfma_f32_16x16x32_bf16(vones, pf[g][0], lsum[g], 0, 0, 0);
            lsum[g] = __builtin_amdgcn_mfma_f32_16x16x32_bf16(vones, pf[g][1], lsum[g], 0, 0, 0);
        }

        // O^T += V^T P^T ; sigma-permuted V fragment = ONE b128 per (dt,tv)
#pragma unroll
        for (int dt = 0; dt < 4; ++dt) {
            const unsigned short* vr = &Vlc[(dt * 16 + l16) * 64];
#pragma unroll
            for (int tv = 0; tv < 2; ++tv) {
                const v8s vvs = *(const v8s*)(vr + voffN[tv]);
#pragma unroll
                for (int g = 0; g < 2; ++g)
                    O[dt][g] = __builtin_amdgcn_mfma_f32_16x16x32_bf16(vvs, pf[g][tv], O[dt][g], 0, 0, 0);
            }
        }
    }

    unsigned short* Ob = Opart + (size_t)blk * 8192;
#pragma unroll
    for (int g = 0; g < 2; ++g) {
        const int row = w * 32 + g * 16 + l16;
#pragma unroll
        for (int dt = 0; dt < 4; ++dt) {
            uint2 u = make_uint2(pkbf(O[dt][g][0], O[dt][g][1]),
                                 pkbf(O[dt][g][2], O[dt][g][3]));
            *(uint2*)(Ob + row * 64 + dt * 16 + quad * 4) = u;
        }
        if (quad == 0) Lbuf[blk * 128 + row] = lsum[g][0];
    }
}

// ---- fused split-reduce + 1/l + output projection (NSPLIT=8).
// 256 blocks x 512 threads. Phase 1: reduce 16 rows over 8 splits, normalize,
// split to bf16 hi/lo A-planes in LDS. Phase 2: 8 waves x 32 cols GEMM.
__global__ __launch_bounds__(512) void oproj_kernel(
    const unsigned short* __restrict__ Opart, const float* __restrict__ Lbuf,
    const unsigned short* __restrict__ WoH, const unsigned short* __restrict__ WoL,
    const float* __restrict__ bo, float* __restrict__ out)
{
    __shared__ alignas(16) unsigned short AH[16][264];
    __shared__ alignas(16) unsigned short AL[16][264];

    const int blk = blockIdx.x;       // 16 rows per block
    const int n0 = blk * 16;
    const int qt = n0 >> 7, rr0 = n0 & 127;
    const int t = threadIdx.x;

    {   // phase 1
        const int row = t >> 5;        // 0..15
        const int d0 = (t & 31) * 8;   // 0..248 (stays within one head: 8 | 64)
        const int h = d0 >> 6, dd0 = d0 & 63;
        const int rr = rr0 + row;
        const int base = qt * 32 + h * 8;   // attn blk = qt*32 + h*8 + s
        const unsigned short* op = Opart + (size_t)base * 8192 + rr * 64 + dd0;
        float lsum = 0.f;
        float o[8] = {0.f, 0.f, 0.f, 0.f, 0.f, 0.f, 0.f, 0.f};
#pragma unroll
        for (int s = 0; s < NSPLIT; ++s) {
            lsum += Lbuf[(base + s) * 128 + rr];
            v8s a = *(const v8s*)(op + (size_t)s * 8192);
#pragma unroll
            for (int j = 0; j < 8; ++j) o[j] += bf2f((unsigned short)a[j]);
        }
        const float inv = 1.f / lsum;
#pragma unroll
        for (int j = 0; j < 8; ++j) o[j] *= inv;
        v8s hi, lo;
        split8(o, hi, lo);
        *(v8s*)&AH[row][d0] = hi;
        *(v8s*)&AL[row][d0] = lo;
    }
    __syncthreads();

    // phase 2: [16 x 256] @ [256 x 256] GEMM, 8 waves x 32 cols
    const int w = t >> 6, lane = t & 63;
    const int quad = lane >> 4, l16 = lane & 15;
    const int colbase = w * 32;
    v4f acc[2];
#pragma unroll
    for (int ct = 0; ct < 2; ++ct) {
        const float bb = bo[colbase + ct * 16 + l16];
        acc[ct] = v4f{bb, bb, bb, bb};
    }
#pragma unroll
    for (int k0 = 0; k0 < 256; k0 += 32) {
        const v8s ah = *(const v8s*)&AH[l16][k0 + quad * 8];
        const v8s al = *(const v8s*)&AL[l16][k0 + quad * 8];
#pragma unroll
        for (int ct = 0; ct < 2; ++ct) {
            v8s wh, wl;
            wload(WoH, WoL, k0 + quad * 8, colbase + ct * 16 + l16, wh, wl);
            acc[ct] = __builtin_amdgcn_mfma_f32_16x16x32_bf16(al, wh, acc[ct], 0, 0, 0);
            acc[ct] = __builtin_amdgcn_mfma_f32_16x16x32_bf16(ah, wl, acc[ct], 0, 0, 0);
            acc[ct] = __builtin_amdgcn_mfma_f32_16x16x32_bf16(ah, wh, acc[ct], 0, 0, 0);
        }
    }
#pragma unroll
    for (int ct = 0; ct < 2; ++ct)
#pragma unroll
        for (int r = 0; r < 4; ++r)
            out[(size_t)(n0 + quad * 4 + r) * 256 + colbase + ct * 16 + l16] = acc[ct][r];
}

extern "C" void kernel_launch(void* const* d_in, const int* in_sizes, int n_in,
                              void* d_out, int out_size, void* d_ws, size_t ws_size,
                              hipStream_t stream) {
    const float* query = (const float*)d_in[0];
    const float* key   = (const float*)d_in[1];
    const float* value = (const float*)d_in[2];
    const float* Wq    = (const float*)d_in[3];
    const float* bq    = (const float*)d_in[4];
    const float* Wk    = (const float*)d_in[5];
    const float* bk    = (const float*)d_in[6];
    const float* Wv    = (const float*)d_in[7];
    const float* bv    = (const float*)d_in[8];
    const float* Wo    = (const float*)d_in[9];
    const float* bo    = (const float*)d_in[10];
    const int*   nex   = (const int*)d_in[11];

    char* ws = (char*)d_ws;
    const size_t MB = 1024 * 1024;
    unsigned short* Qb    = (unsigned short*)(ws);                    // 2 MB
    unsigned short* Kb    = (unsigned short*)(ws + 2 * MB);           // 4 MB
    unsigned short* Vt    = (unsigned short*)(ws + 6 * MB);           // 4 MB
    unsigned short* Opart = (unsigned short*)(ws + 10 * MB);          // 16 MB bf16 (8 splits)
    float* Lbuf           = (float*)(ws + 26 * MB);                   // 512 KB
    unsigned short* Wpl   = (unsigned short*)(ws + 26 * MB + 512 * 1024);  // 640 KB
    unsigned short* WqH = Wpl;
    unsigned short* WqL = Wpl + 65536;
    unsigned short* WkH = Wpl + 131072;
    unsigned short* WkL = Wpl + 147456;
    unsigned short* WvH = Wpl + 163840;
    unsigned short* WvL = Wpl + 180224;
    unsigned short* WoH = Wpl + 196608;
    unsigned short* WoL = Wpl + 262144;
    float* out = (float*)d_out;

    prep_kernel<<<80, 256, 0, stream>>>(Wq, Wk, Wv, Wo,
                                        WqH, WqL, WkH, WkL, WvH, WvL, WoH, WoL);
    qkv_kernel<<<1280, 256, 0, stream>>>(query, key, value,
                                         WqH, WqL, WkH, WkL, WvH, WvL,
                                         bq, bk, bv, Qb, Kb, Vt, nex);
    attn_kernel<<<1024, 256, 0, stream>>>(Qb, Kb, Vt, Opart, Lbuf);
    oproj_kernel<<<256, 512, 0, stream>>>(Opart, Lbuf, WoH, WoL, bo, out);
}

// Round 9
// 149.906 us; speedup vs baseline: 1.8688x; 1.0060x over previous
//
#include <hip/hip_runtime.h>
#include <hip/hip_bf16.h>

#define NQ 4096
#define NK 8192
#define NSPLIT 8
#define KSPAN (NK / NSPLIT)
#define BK 64

// 0.125 (1/sqrt(64)) * log2(e): scores in log2 domain; no max subtraction needed
// (|S| <= ~14 in log2 domain, exp2 can't overflow; scale cancels in O/l)
#define QSCALE 0.1803368801111204f

typedef short v8s __attribute__((ext_vector_type(8)));
typedef float v4f __attribute__((ext_vector_type(4)));

static __device__ __forceinline__ unsigned short f2bf(float f) {
    unsigned int u = __float_as_uint(f);
    u = (u + 0x7FFFu + ((u >> 16) & 1u)) >> 16;
    return (unsigned short)u;
}
static __device__ __forceinline__ float bf2f(unsigned short h) {
    return __uint_as_float(((unsigned int)h) << 16);
}
static __device__ __forceinline__ unsigned int pkbf(float a, float b) {
    union { __hip_bfloat162 h; unsigned int u; } cv;
    cv.h = __float22bfloat162_rn(make_float2(a, b));
    return cv.u;
}
static __device__ __forceinline__ void split8(const float* a, v8s& hi, v8s& lo) {
#pragma unroll
    for (int j = 0; j < 8; ++j) {
        unsigned short h = f2bf(a[j]);
        hi[j] = (short)h;
        lo[j] = (short)f2bf(a[j] - bf2f(h));
    }
}
// load pre-split W^T B-fragment (hi/lo planes, layout [(k0>>3)*256+col][8])
static __device__ __forceinline__ void wload(const unsigned short* __restrict__ H,
                                             const unsigned short* __restrict__ L,
                                             int k0, int col, v8s& wh, v8s& wl) {
    const size_t f = (size_t)((k0 >> 3) * 256 + col) * 8;
    wh = *(const v8s*)(H + f);
    wl = *(const v8s*)(L + f);
}
// async global->LDS, 16B/lane; dest = uniform base + lane*16
static __device__ __forceinline__ void dma16(const unsigned short* g, unsigned short* l) {
    __builtin_amdgcn_global_load_lds(
        (const __attribute__((address_space(1))) unsigned int*)(const void*)g,
        (__attribute__((address_space(3))) unsigned int*)(void*)l, 16, 0, 0);
}

// ---- weight pre-split: f32 W[K][256] -> bf16 hi/lo planes in fragment layout
__global__ __launch_bounds__(256) void prep_kernel(
    const float* __restrict__ Wq, const float* __restrict__ Wk,
    const float* __restrict__ Wv, const float* __restrict__ Wo,
    unsigned short* __restrict__ WqH, unsigned short* __restrict__ WqL,
    unsigned short* __restrict__ WkH, unsigned short* __restrict__ WkL,
    unsigned short* __restrict__ WvH, unsigned short* __restrict__ WvL,
    unsigned short* __restrict__ WoH, unsigned short* __restrict__ WoL)
{
    const int tid = blockIdx.x * 256 + threadIdx.x;  // 20480 total
    const float* W;
    unsigned short *H, *L;
    int f;
    if (tid < 8192)        { W = Wq; H = WqH; L = WqL; f = tid; }
    else if (tid < 10240)  { W = Wk; H = WkH; L = WkL; f = tid - 8192; }
    else if (tid < 12288)  { W = Wv; H = WvH; L = WvL; f = tid - 10240; }
    else                   { W = Wo; H = WoH; L = WoL; f = tid - 12288; }
    const int col = f & 255, k0 = (f >> 8) << 3;
    float wv[8];
#pragma unroll
    for (int j = 0; j < 8; ++j) wv[j] = W[(size_t)(k0 + j) * 256 + col];
    v8s hi, lo;
    split8(wv, hi, lo);
    *(v8s*)(H + (size_t)f * 8) = hi;
    *(v8s*)(L + (size_t)f * 8) = lo;
}

// ---- fused QKV projection with pre-split weights
__global__ __launch_bounds__(256) void qkv_kernel(
    const float* __restrict__ query, const float* __restrict__ key,
    const float* __restrict__ value,
    const unsigned short* __restrict__ WqH, const unsigned short* __restrict__ WqL,
    const unsigned short* __restrict__ WkH, const unsigned short* __restrict__ WkL,
    const unsigned short* __restrict__ WvH, const unsigned short* __restrict__ WvL,
    const float* __restrict__ bq, const float* __restrict__ bk,
    const float* __restrict__ bv,
    unsigned short* __restrict__ Qb, unsigned short* __restrict__ Kb,
    unsigned short* __restrict__ Vt, const int* __restrict__ nexp)
{
    const int b = blockIdx.x;
    const int t = threadIdx.x, w = t >> 6, lane = t & 63;
    const int quad = lane >> 4, l16 = lane & 15;
    const int colbase = w * 64;

    if (b < 256) {
        const int n0 = b * 16;
        v4f acc[4];
#pragma unroll
        for (int ct = 0; ct < 4; ++ct) {
            const float bb = bq[colbase + ct * 16 + l16];
            acc[ct] = v4f{bb, bb, bb, bb};
        }
        const float* arow = query + (size_t)(n0 + l16) * 256 + quad * 8;
#pragma unroll
        for (int k0 = 0; k0 < 256; k0 += 32) {
            float av[8];
            *(float4*)av = *(const float4*)(arow + k0);
            *(float4*)(av + 4) = *(const float4*)(arow + k0 + 4);
            v8s ah, al;
            split8(av, ah, al);
#pragma unroll
            for (int ct = 0; ct < 4; ++ct) {
                v8s wh, wl;
                wload(WqH, WqL, k0 + quad * 8, colbase + ct * 16 + l16, wh, wl);
                acc[ct] = __builtin_amdgcn_mfma_f32_16x16x32_bf16(al, wh, acc[ct], 0, 0, 0);
                acc[ct] = __builtin_amdgcn_mfma_f32_16x16x32_bf16(ah, wl, acc[ct], 0, 0, 0);
                acc[ct] = __builtin_amdgcn_mfma_f32_16x16x32_bf16(ah, wh, acc[ct], 0, 0, 0);
            }
        }
#pragma unroll
        for (int ct = 0; ct < 4; ++ct) {
            const int d = ct * 16 + l16;
            const int j = d >> 1;
            const float freq = exp2f(-(float)(j & 15) * 1.66096404744368f);
            const bool isx = (j < 16), odd = (d & 1);
#pragma unroll
            for (int r = 0; r < 4; ++r) {
                const int p = n0 + quad * 4 + r;
                const float tpos = isx ? (float)(p & 63) : (float)(p >> 6);
                float sn, cs;
                __sincosf(tpos * freq, &sn, &cs);
                const float x = acc[ct][r];
                const float xp = __shfl_xor(x, 1, 64);
                const float y = odd ? fmaf(x, cs, xp * sn) : fmaf(x, cs, -xp * sn);
                Qb[((size_t)(w * NQ + p) << 6) + d] = f2bf(y * QSCALE);
            }
        }
    } else {
        const bool isK = (b < 768);
        const int n0 = (isK ? (b - 256) : (b - 768)) * 16;
        const float* X = isK ? key : value;
        const unsigned short* WH = isK ? WkH : WvH;
        const unsigned short* WL = isK ? WkL : WvL;
        const float* bias = isK ? bk : bv;
        v4f acc[4];
#pragma unroll
        for (int ct = 0; ct < 4; ++ct) {
            const float bb = bias[colbase + ct * 16 + l16];
            acc[ct] = v4f{bb, bb, bb, bb};
        }
        const float* arow = X + (size_t)(n0 + l16) * 64 + quad * 8;
#pragma unroll
        for (int k0 = 0; k0 < 64; k0 += 32) {
            float av[8];
            *(float4*)av = *(const float4*)(arow + k0);
            *(float4*)(av + 4) = *(const float4*)(arow + k0 + 4);
            v8s ah, al;
            split8(av, ah, al);
#pragma unroll
            for (int ct = 0; ct < 4; ++ct) {
                v8s wh, wl;
                wload(WH, WL, k0 + quad * 8, colbase + ct * 16 + l16, wh, wl);
                acc[ct] = __builtin_amdgcn_mfma_f32_16x16x32_bf16(al, wh, acc[ct], 0, 0, 0);
                acc[ct] = __builtin_amdgcn_mfma_f32_16x16x32_bf16(ah, wl, acc[ct], 0, 0, 0);
                acc[ct] = __builtin_amdgcn_mfma_f32_16x16x32_bf16(ah, wh, acc[ct], 0, 0, 0);
            }
        }
        if (isK) {
            const int nro = NK - *nexp;
#pragma unroll
            for (int ct = 0; ct < 4; ++ct) {
                const int d = ct * 16 + l16;
                const int j = d >> 1;
                const float freq = exp2f(-(float)(j & 15) * 1.66096404744368f);
                const bool isx = (j < 16), odd = (d & 1);
#pragma unroll
                for (int r = 0; r < 4; ++r) {
                    const int p = n0 + quad * 4 + r;
                    const int pc = p & 4095;
                    const float tpos = isx ? (float)(pc & 63) : (float)(pc >> 6);
                    float sn, cs;
                    __sincosf(tpos * freq, &sn, &cs);
                    const float x = acc[ct][r];
                    const float xp = __shfl_xor(x, 1, 64);
                    float y = odd ? fmaf(x, cs, xp * sn) : fmaf(x, cs, -xp * sn);
                    y = (p < nro) ? y : x;
                    Kb[((size_t)(w * NK + p) << 6) + d] = f2bf(y);
                }
            }
        } else {
            // interleaved k-layout within each 64-group: 4-elem piece s=(k&63)>>2
            // stored at 16B-chunk (4*(s>>3) + (s&3)), 8B-half ((s>>2)&1).
            // -> attn's PV reads each sigma-permuted V fragment as ONE b128.
            const int s0 = ((n0 & 63) >> 2) + quad;   // piece index 0..15
            const int tv = s0 >> 3, m = s0 & 7;
            const int koff = (n0 & ~63) + ((4 * tv + (m & 3)) << 3) + ((m >> 2) << 2);
#pragma unroll
            for (int ct = 0; ct < 4; ++ct) {
                const int col = colbase + ct * 16 + l16;
                uint2 u = make_uint2(pkbf(acc[ct][0], acc[ct][1]),
                                     pkbf(acc[ct][2], acc[ct][3]));
                *(uint2*)(Vt + (size_t)col * NK + koff) = u;
            }
        }
    }
}

// one attention tile's compute: QK^T -> exp2 -> pack -> lsum MFMA -> PV MFMA.
// Byte-identical math to R8; factored out so the caller can pass a
// compile-time LDS buffer (cur is static after unroll-by-2).
static __device__ __forceinline__ void attn_tile_compute(
    const unsigned short* __restrict__ Klc, const unsigned short* __restrict__ Vlc,
    const v8s (&qf)[2][2], v4f (&O)[4][2], v4f (&lsum)[2], const v8s vones,
    const int l16, const int c0off, const int c1off, const int (&voffN)[2])
{
    v8s pf[2][2]; // [g][t]: slots 0-3 <- e[2t][0..3], slots 4-7 <- e[2t+1][0..3]
#pragma unroll
    for (int tt = 0; tt < 4; ++tt) {
        const unsigned short* kr = &Klc[(tt * 16 + l16) * 64];
        const v8s kf0 = *(const v8s*)(kr + c0off);
        const v8s kf1 = *(const v8s*)(kr + c1off);
#pragma unroll
        for (int g = 0; g < 2; ++g) {
            v4f a = v4f{0.f, 0.f, 0.f, 0.f};
            a = __builtin_amdgcn_mfma_f32_16x16x32_bf16(kf0, qf[g][0], a, 0, 0, 0);
            a = __builtin_amdgcn_mfma_f32_16x16x32_bf16(kf1, qf[g][1], a, 0, 0, 0);
            const float e0 = __builtin_amdgcn_exp2f(a[0]);
            const float e1 = __builtin_amdgcn_exp2f(a[1]);
            const float e2 = __builtin_amdgcn_exp2f(a[2]);
            const float e3 = __builtin_amdgcn_exp2f(a[3]);
            unsigned int* pp = (unsigned int*)&pf[g][tt >> 1];
            pp[(tt & 1) * 2 + 0] = pkbf(e0, e1);
            pp[(tt & 1) * 2 + 1] = pkbf(e2, e3);
        }
    }

    // l-sum: column sums of pf via ones-MFMA (idle matrix pipe)
#pragma unroll
    for (int g = 0; g < 2; ++g) {
        lsum[g] = __builtin_amdgcn_mfma_f32_16x16x32_bf16(vones, pf[g][0], lsum[g], 0, 0, 0);
        lsum[g] = __builtin_amdgcn_mfma_f32_16x16x32_bf16(vones, pf[g][1], lsum[g], 0, 0, 0);
    }

    // O^T += V^T P^T ; sigma-permuted V fragment = ONE b128 per (dt,tv)
#pragma unroll
    for (int dt = 0; dt < 4; ++dt) {
        const unsigned short* vr = &Vlc[(dt * 16 + l16) * 64];
#pragma unroll
        for (int tv = 0; tv < 2; ++tv) {
            const v8s vvs = *(const v8s*)(vr + voffN[tv]);
#pragma unroll
            for (int g = 0; g < 2; ++g)
                O[dt][g] = __builtin_amdgcn_mfma_f32_16x16x32_bf16(vvs, pf[g][tv], O[dt][g], 0, 0, 0);
        }
    }
}

// ---- flash attention: 1024 blocks = qt(32) x h(4) x s(8); 4 waves x 32 q-rows
// R9: R8 + addressing strength-reduction: staging uses 4 stride-incremented
// global pointers (2 VALU each/tile vs full 64-bit rebuilds); main loop unrolled
// by 2 so `cur` is compile-time (LDS bases fold to immediates); last two tiles
// peeled so the prefetch guard vanishes from the steady-state body.
__global__ __launch_bounds__(256) void attn_kernel(
    const unsigned short* __restrict__ Qb, const unsigned short* __restrict__ Kb,
    const unsigned short* __restrict__ Vt, unsigned short* __restrict__ Opart,
    float* __restrict__ Lbuf)
{
    __shared__ alignas(16) unsigned short Kl[2][64 * 64];
    __shared__ alignas(16) unsigned short Vl[2][64 * 64];

    const int blk = blockIdx.x;
    const int s = blk & 7, h = (blk >> 3) & 3, qt = blk >> 5;
    const int t = threadIdx.x;
    const int w = t >> 6, lane = t & 63;
    const int quad = lane >> 4, l16 = lane & 15;

    const int q0 = qt * 128 + w * 32;
    v8s qf[2][2];
#pragma unroll
    for (int g = 0; g < 2; ++g) {
        const unsigned short* qr = Qb + ((size_t)(h * NQ + q0 + g * 16 + l16) << 6) + quad * 8;
        qf[g][0] = *(const v8s*)qr;
        qf[g][1] = *(const v8s*)(qr + 32);
    }

    v4f O[4][2];
#pragma unroll
    for (int dt = 0; dt < 4; ++dt)
#pragma unroll
        for (int g = 0; g < 2; ++g) O[dt][g] = v4f{0.f, 0.f, 0.f, 0.f};
    v4f lsum[2];
    lsum[0] = v4f{0.f, 0.f, 0.f, 0.f};
    lsum[1] = v4f{0.f, 0.f, 0.f, 0.f};
    const short one_bf = (short)0x3F80;  // bf16 1.0
    const v8s vones = v8s{one_bf, one_bf, one_bf, one_bf, one_bf, one_bf, one_bf, one_bf};

    const unsigned short* Kbase = Kb + (((size_t)h * NK + s * KSPAN) << 6);
    const unsigned short* Vbase = Vt + (size_t)(h * 64) * NK + s * KSPAN;

    const int srow = lane >> 3;            // 0..7
    const int schunk = (lane & 7) ^ srow;  // swizzled 16B chunk
    const int c0off = ((quad ^ (l16 & 7)) * 8);
    const int c1off = c0off ^ 32;
    int voffN[2];
#pragma unroll
    for (int tv = 0; tv < 2; ++tv)
        voffN[tv] = ((4 * tv + quad) ^ (l16 & 7)) << 3;

    // per-wave staging pointers (tile 0), advanced by constant strides per tile
    const unsigned short* kpre0 = Kbase + ((size_t)(w * 16 + 0 + srow) << 6) + schunk * 8;
    const unsigned short* kpre1 = Kbase + ((size_t)(w * 16 + 8 + srow) << 6) + schunk * 8;
    const unsigned short* vpre0 = Vbase + (size_t)(w * 16 + 0 + srow) * NK + schunk * 8;
    const unsigned short* vpre1 = Vbase + (size_t)(w * 16 + 8 + srow) * NK + schunk * 8;
    const int ldb = w << 10;  // per-wave LDS row base (w*16*64)

    // prologue: stage tile 0 into buffer 0, then advance pointers to tile 1
    dma16(kpre0, &Kl[0][ldb]);
    dma16(kpre1, &Kl[0][ldb + 512]);
    dma16(vpre0, &Vl[0][ldb]);
    dma16(vpre1, &Vl[0][ldb + 512]);
    kpre0 += (BK << 6); kpre1 += (BK << 6);
    vpre0 += BK;        vpre1 += BK;

    // steady state: tiles 0..13 as 7 unrolled pairs (cur = 0 then 1, both with
    // prefetch); pointers always point at tile it+1 when the prefetch issues.
#pragma unroll 1
    for (int ii = 0; ii < 7; ++ii) {
        __syncthreads();
        dma16(kpre0, &Kl[1][ldb]);
        dma16(kpre1, &Kl[1][ldb + 512]);
        dma16(vpre0, &Vl[1][ldb]);
        dma16(vpre1, &Vl[1][ldb + 512]);
        kpre0 += (BK << 6); kpre1 += (BK << 6);
        vpre0 += BK;        vpre1 += BK;
        attn_tile_compute(&Kl[0][0], &Vl[0][0], qf, O, lsum, vones, l16, c0off, c1off, voffN);

        __syncthreads();
        dma16(kpre0, &Kl[0][ldb]);
        dma16(kpre1, &Kl[0][ldb + 512]);
        dma16(vpre0, &Vl[0][ldb]);
        dma16(vpre1, &Vl[0][ldb + 512]);
        kpre0 += (BK << 6); kpre1 += (BK << 6);
        vpre0 += BK;        vpre1 += BK;
        attn_tile_compute(&Kl[1][0], &Vl[1][0], qf, O, lsum, vones, l16, c0off, c1off, voffN);
    }
    // tile 14 (cur=0): prefetch tile 15 into buffer 1
    __syncthreads();
    dma16(kpre0, &Kl[1][ldb]);
    dma16(kpre1, &Kl[1][ldb + 512]);
    dma16(vpre0, &Vl[1][ldb]);
    dma16(vpre1, &Vl[1][ldb + 512]);
    attn_tile_compute(&Kl[0][0], &Vl[0][0], qf, O, lsum, vones, l16, c0off, c1off, voffN);
    // tile 15 (cur=1): no prefetch
    __syncthreads();
    attn_tile_compute(&Kl[1][0], &Vl[1][0], qf, O, lsum, vones, l16, c0off, c1off, voffN);

    unsigned short* Ob = Opart + (size_t)blk * 8192;
#pragma unroll
    for (int g = 0; g < 2; ++g) {
        const int row = w * 32 + g * 16 + l16;
#pragma unroll
        for (int dt = 0; dt < 4; ++dt) {
            uint2 u = make_uint2(pkbf(O[dt][g][0], O[dt][g][1]),
                                 pkbf(O[dt][g][2], O[dt][g][3]));
            *(uint2*)(Ob + row * 64 + dt * 16 + quad * 4) = u;
        }
        if (quad == 0) Lbuf[blk * 128 + row] = lsum[g][0];
    }
}

// ---- fused split-reduce + 1/l + output projection (NSPLIT=8).
// 256 blocks x 512 threads. Phase 1: reduce 16 rows over 8 splits, normalize,
// split to bf16 hi/lo A-planes in LDS. Phase 2: 8 waves x 32 cols GEMM.
__global__ __launch_bounds__(512) void oproj_kernel(
    const unsigned short* __restrict__ Opart, const float* __restrict__ Lbuf,
    const unsigned short* __restrict__ WoH, const unsigned short* __restrict__ WoL,
    const float* __restrict__ bo, float* __restrict__ out)
{
    __shared__ alignas(16) unsigned short AH[16][264];
    __shared__ alignas(16) unsigned short AL[16][264];

    const int blk = blockIdx.x;       // 16 rows per block
    const int n0 = blk * 16;
    const int qt = n0 >> 7, rr0 = n0 & 127;
    const int t = threadIdx.x;

    {   // phase 1
        const int row = t >> 5;        // 0..15
        const int d0 = (t & 31) * 8;   // 0..248 (stays within one head: 8 | 64)
        const int h = d0 >> 6, dd0 = d0 & 63;
        const int rr = rr0 + row;
        const int base = qt * 32 + h * 8;   // attn blk = qt*32 + h*8 + s
        const unsigned short* op = Opart + (size_t)base * 8192 + rr * 64 + dd0;
        float lsum = 0.f;
        float o[8] = {0.f, 0.f, 0.f, 0.f, 0.f, 0.f, 0.f, 0.f};
#pragma unroll
        for (int s = 0; s < NSPLIT; ++s) {
            lsum += Lbuf[(base + s) * 128 + rr];
            v8s a = *(const v8s*)(op + (size_t)s * 8192);
#pragma unroll
            for (int j = 0; j < 8; ++j) o[j] += bf2f((unsigned short)a[j]);
        }
        const float inv = 1.f / lsum;
#pragma unroll
        for (int j = 0; j < 8; ++j) o[j] *= inv;
        v8s hi, lo;
        split8(o, hi, lo);
        *(v8s*)&AH[row][d0] = hi;
        *(v8s*)&AL[row][d0] = lo;
    }
    __syncthreads();

    // phase 2: [16 x 256] @ [256 x 256] GEMM, 8 waves x 32 cols
    const int w = t >> 6, lane = t & 63;
    const int quad = lane >> 4, l16 = lane & 15;
    const int colbase = w * 32;
    v4f acc[2];
#pragma unroll
    for (int ct = 0; ct < 2; ++ct) {
        const float bb = bo[colbase + ct * 16 + l16];
        acc[ct] = v4f{bb, bb, bb, bb};
    }
#pragma unroll
    for (int k0 = 0; k0 < 256; k0 += 32) {
        const v8s ah = *(const v8s*)&AH[l16][k0 + quad * 8];
        const v8s al = *(const v8s*)&AL[l16][k0 + quad * 8];
#pragma unroll
        for (int ct = 0; ct < 2; ++ct) {
            v8s wh, wl;
            wload(WoH, WoL, k0 + quad * 8, colbase + ct * 16 + l16, wh, wl);
            acc[ct] = __builtin_amdgcn_mfma_f32_16x16x32_bf16(al, wh, acc[ct], 0, 0, 0);
            acc[ct] = __builtin_amdgcn_mfma_f32_16x16x32_bf16(ah, wl, acc[ct], 0, 0, 0);
            acc[ct] = __builtin_amdgcn_mfma_f32_16x16x32_bf16(ah, wh, acc[ct], 0, 0, 0);
        }
    }
#pragma unroll
    for (int ct = 0; ct < 2; ++ct)
#pragma unroll
        for (int r = 0; r < 4; ++r)
            out[(size_t)(n0 + quad * 4 + r) * 256 + colbase + ct * 16 + l16] = acc[ct][r];
}

extern "C" void kernel_launch(void* const* d_in, const int* in_sizes, int n_in,
                              void* d_out, int out_size, void* d_ws, size_t ws_size,
                              hipStream_t stream) {
    const float* query = (const float*)d_in[0];
    const float* key   = (const float*)d_in[1];
    const float* value = (const float*)d_in[2];
    const float* Wq    = (const float*)d_in[3];
    const float* bq    = (const float*)d_in[4];
    const float* Wk    = (const float*)d_in[5];
    const float* bk    = (const float*)d_in[6];
    const float* Wv    = (const float*)d_in[7];
    const float* bv    = (const float*)d_in[8];
    const float* Wo    = (const float*)d_in[9];
    const float* bo    = (const float*)d_in[10];
    const int*   nex   = (const int*)d_in[11];

    char* ws = (char*)d_ws;
    const size_t MB = 1024 * 1024;
    unsigned short* Qb    = (unsigned short*)(ws);                    // 2 MB
    unsigned short* Kb    = (unsigned short*)(ws + 2 * MB);           // 4 MB
    unsigned short* Vt    = (unsigned short*)(ws + 6 * MB);           // 4 MB
    unsigned short* Opart = (unsigned short*)(ws + 10 * MB);          // 16 MB bf16 (8 splits)
    float* Lbuf           = (float*)(ws + 26 * MB);                   // 512 KB
    unsigned short* Wpl   = (unsigned short*)(ws + 26 * MB + 512 * 1024);  // 640 KB
    unsigned short* WqH = Wpl;
    unsigned short* WqL = Wpl + 65536;
    unsigned short* WkH = Wpl + 131072;
    unsigned short* WkL = Wpl + 147456;
    unsigned short* WvH = Wpl + 163840;
    unsigned short* WvL = Wpl + 180224;
    unsigned short* WoH = Wpl + 196608;
    unsigned short* WoL = Wpl + 262144;
    float* out = (float*)d_out;

    prep_kernel<<<80, 256, 0, stream>>>(Wq, Wk, Wv, Wo,
                                        WqH, WqL, WkH, WkL, WvH, WvL, WoH, WoL);
    qkv_kernel<<<1280, 256, 0, stream>>>(query, key, value,
                                         WqH, WqL, WkH, WkL, WvH, WvL,
                                         bq, bk, bv, Qb, Kb, Vt, nex);
    attn_kernel<<<1024, 256, 0, stream>>>(Qb, Kb, Vt, Opart, Lbuf);
    oproj_kernel<<<256, 512, 0, stream>>>(Opart, Lbuf, WoH, WoL, bo, out);
}